// Round 10
// baseline (353.379 us; speedup 1.0000x reference)
//
#include <hip/hip_runtime.h>
#include <math.h>

#define NTOK 16384
#define HDIM 2048
#define NEXP 64
#define KK   32
#define TAU  5e-5f
#define MAXB 2048    // bucket capacity per expert (mean 256, 112 sigma margin)
#define KP2  40      // LDS u16 row stride
#define LTS2 68      // epilogue f32 row stride

typedef __attribute__((ext_vector_type(8))) short short8;
typedef __attribute__((ext_vector_type(4))) float f32x4;
typedef __attribute__((ext_vector_type(2))) unsigned int uint2v;

// ws layout (4-byte units):
// [0..64)              inv_nc (f32)
// [64..128)            cursor (i32)
// [128..192)           nflag + pad (i32)
// [192..16576)         route  (i32)
// [16576..32960)       flags  (i32)
// [32960..164032)      sums   (f32, 64x2048)  (fallback path only)
// [164032..295104)     bn     (f32, 64x2048)
// [295104..360640)     cbh    (u16, 64x2048)
// [360640..426176)     cbl    (u16, 64x2048)
// [426176..557248)     bucket (i32, 64x2048)
// [557248..1081536)    psum   (f32, 4x64x2048)
// [1081536..1097920)   posa   (i32, 16384)
// [1097920..1097984)   cnt    (i32, 64)
// [1097984..9486592)   lp     (f32, 8x64x16384)  partial logits
// [9486592..9617664)   xnp    (f32, 8x16384)     partial xnorm2

__global__ __launch_bounds__(256)
void zero_kernel(float* p, int n) {
  int i = blockIdx.x * 256 + threadIdx.x;
  if (i < n) p[i] = 0.0f;
}

__device__ __forceinline__ float block_reduce_sum(float v, float* red) {
  #pragma unroll
  for (int o = 32; o > 0; o >>= 1) v += __shfl_down(v, o, 64);
  int lane = threadIdx.x & 63;
  int wid  = threadIdx.x >> 6;
  if (lane == 0) red[wid] = v;
  __syncthreads();
  float s = red[0] + red[1] + red[2] + red[3];
  __syncthreads();
  return s;
}

__device__ __forceinline__ double block_reduce_sum_f64(double v, double* red) {
  const int tid = threadIdx.x;
  red[tid] = v;
  __syncthreads();
  if (tid < 128) red[tid] += red[tid + 128];
  __syncthreads();
  if (tid < 64)  red[tid] += red[tid + 64];
  __syncthreads();
  double s = 0.0;
  if (tid < 64) {
    s = red[tid];
    #pragma unroll
    for (int o = 32; o > 0; o >>= 1) s += __shfl_down(s, o, 64);
  }
  if (tid == 0) red[0] = s;
  __syncthreads();
  s = red[0];
  __syncthreads();
  return s;
}

__global__ __launch_bounds__(256)
void cnorm_kernel(const float* __restrict__ c, float* __restrict__ inv_nc) {
  __shared__ float red[4];
  int e = blockIdx.x;
  float ss = 0.f;
  #pragma unroll
  for (int j = 0; j < 8; ++j) {
    float v = c[e * HDIM + threadIdx.x + j * 256];
    ss += v * v;
  }
  float tot = block_reduce_sum(ss, red);
  if (threadIdx.x == 0) inv_nc[e] = 1.0f / fmaxf(sqrtf(tot), 1e-12f);
}

// Center prep: fp32 inv-norm, fp64 bn, bf16 hi/lo split of c, zero counters.
__global__ __launch_bounds__(256)
void cprep_kernel(const float* __restrict__ c, float* __restrict__ inv_nc,
                  float* __restrict__ bn, unsigned short* __restrict__ cbh,
                  unsigned short* __restrict__ cbl, int* __restrict__ zr,
                  int* __restrict__ cnt) {
  __shared__ float red[4];
  __shared__ double redd[256];
  __shared__ float s_nc;
  const int e = blockIdx.x;
  const int tid = threadIdx.x;
  if (e == 0 && tid < 128) zr[tid] = 0;   // cursor[64] + nflag block
  if (e == 1 && tid < 64)  cnt[tid] = 0;
  const float* cr = c + (size_t)e * HDIM;
  float ss = 0.f;
  double acc = 0.0;
  #pragma unroll
  for (int j = 0; j < 8; ++j) {
    float v = cr[tid + j * 256];
    ss += v * v;
    double dv = (double)v;
    acc += dv * dv;
  }
  float tot = block_reduce_sum(ss, red);
  double cn = block_reduce_sum_f64(acc, redd);
  if (tid == 0) {
    inv_nc[e] = 1.0f / fmaxf(sqrtf(tot), 1e-12f);
    s_nc = (float)fmax(sqrt(cn), 1e-12);
  }
  __syncthreads();
  const double nc = (double)s_nc;
  #pragma unroll
  for (int j = 0; j < 8; ++j) {
    const int k = tid + j * 256;
    const float v = cr[k];
    bn[(size_t)e * HDIM + k] = (float)((double)v / nc);
    unsigned u = __float_as_uint(v);
    unsigned h = u & 0xffff0000u;
    float r = v - __uint_as_float(h);
    cbh[(size_t)e * HDIM + k] = (unsigned short)(u >> 16);
    cbl[(size_t)e * HDIM + k] = (unsigned short)(__float_as_uint(r) >> 16);
  }
}

// split fp32 pair into bf16 hi (truncation) + bf16 lo (truncated residual), packed 2-wide.
__device__ __forceinline__ void cvt2(float v0, float v1, unsigned &hi, unsigned &lo) {
  unsigned u0 = __float_as_uint(v0);
  unsigned u1 = __float_as_uint(v1);
  unsigned h0 = u0 & 0xffff0000u;
  unsigned h1 = u1 & 0xffff0000u;
  float r0 = v0 - __uint_as_float(h0);
  float r1 = v1 - __uint_as_float(h1);
  hi = (u0 >> 16) | h1;
  lo = (__float_as_uint(r0) >> 16) | (__float_as_uint(r1) & 0xffff0000u);
}

// K-split MFMA GEMM v2: block = 64 tokens x 64 experts x K=256. grid = 256 mt x 8 ks.
// 2-deep register prefetch (A/B sets): loads for it+2 issued right after staging,
// consumed two MFMA blocks later (~2 K-iters of latency slack). VGPR stays <128.
__global__ __launch_bounds__(256)
void gemm_part(const float* __restrict__ x,
               const unsigned short* __restrict__ cbh,
               const unsigned short* __restrict__ cbl,
               float* __restrict__ lp, float* __restrict__ xnp) {
  __shared__ __align__(16) unsigned short smem[10240];   // 20 KB
  unsigned short (*Ah)[KP2] = (unsigned short (*)[KP2])(smem);          // 64x40
  unsigned short (*Al)[KP2] = (unsigned short (*)[KP2])(smem + 2560);
  unsigned short (*Bh)[KP2] = (unsigned short (*)[KP2])(smem + 5120);
  unsigned short (*Bl)[KP2] = (unsigned short (*)[KP2])(smem + 7680);

  const int tid  = threadIdx.x;
  const int mt   = blockIdx.x >> 3;
  const int ks   = blockIdx.x & 7;
  const int t0   = mt * 64;
  const int kb   = ks * 256;
  const int sr   = tid >> 2;          // stage row 0..63 (A token / B expert)
  const int sq   = (tid & 3) * 8;     // stage col (8 elems)
  const int lane = tid & 63;
  const int w    = tid >> 6;
  const int tw   = (w & 1) * 32;
  const int ew   = (w >> 1) * 32;
  const int fr   = lane & 15;
  const int fk   = (lane >> 4) * 8;

  const float*          xrow  = x   + (size_t)(t0 + sr) * HDIM + kb + sq;
  const unsigned short* bhrow = cbh + (size_t)sr * HDIM + kb + sq;
  const unsigned short* blrow = cbl + (size_t)sr * HDIM + kb + sq;

  float nacc = 0.f;
  f32x4 Ax0, Ax1, Bx0, Bx1;
  short8 Abh, Abl, Bbh, Bbl;

  f32x4 acc[2][2];
  #pragma unroll
  for (int mi = 0; mi < 2; ++mi)
    #pragma unroll
    for (int ni = 0; ni < 2; ++ni)
      acc[mi][ni] = (f32x4){0.f, 0.f, 0.f, 0.f};

  #define LDREG(P, it_) do { const int o_ = (it_) * KK;                   \
    P##x0 = *(const f32x4*)(xrow + o_);                                   \
    P##x1 = *(const f32x4*)(xrow + o_ + 4);                               \
    P##bh = *(const short8*)(bhrow + o_);                                 \
    P##bl = *(const short8*)(blrow + o_); } while (0)

  #define STAGE(P) do {                                                   \
    unsigned h01, l01, h23, l23, h45, l45, h67, l67;                      \
    cvt2(P##x0.x, P##x0.y, h01, l01);                                     \
    cvt2(P##x0.z, P##x0.w, h23, l23);                                     \
    cvt2(P##x1.x, P##x1.y, h45, l45);                                     \
    cvt2(P##x1.z, P##x1.w, h67, l67);                                     \
    *(uint2v*)&Ah[sr][sq]     = (uint2v){h01, h23};                       \
    *(uint2v*)&Ah[sr][sq + 4] = (uint2v){h45, h67};                       \
    *(uint2v*)&Al[sr][sq]     = (uint2v){l01, l23};                       \
    *(uint2v*)&Al[sr][sq + 4] = (uint2v){l45, l67};                       \
    nacc += P##x0.x*P##x0.x + P##x0.y*P##x0.y + P##x0.z*P##x0.z + P##x0.w*P##x0.w \
          + P##x1.x*P##x1.x + P##x1.y*P##x1.y + P##x1.z*P##x1.z + P##x1.w*P##x1.w; \
    *(short8*)&Bh[sr][sq] = P##bh;                                        \
    *(short8*)&Bl[sr][sq] = P##bl; } while (0)

  #define MFMAS() do {                                                    \
    short8 ah0 = *(const short8*)&Ah[tw + fr][fk];                        \
    short8 ah1 = *(const short8*)&Ah[tw + 16 + fr][fk];                   \
    short8 al0 = *(const short8*)&Al[tw + fr][fk];                        \
    short8 al1 = *(const short8*)&Al[tw + 16 + fr][fk];                   \
    _Pragma("unroll")                                                     \
    for (int ni = 0; ni < 2; ++ni) {                                      \
      short8 bh = *(const short8*)&Bh[ew + ni * 16 + fr][fk];             \
      short8 bl = *(const short8*)&Bl[ew + ni * 16 + fr][fk];             \
      acc[0][ni] = __builtin_amdgcn_mfma_f32_16x16x32_bf16(ah0, bh, acc[0][ni], 0, 0, 0); \
      acc[0][ni] = __builtin_amdgcn_mfma_f32_16x16x32_bf16(ah0, bl, acc[0][ni], 0, 0, 0); \
      acc[0][ni] = __builtin_amdgcn_mfma_f32_16x16x32_bf16(al0, bh, acc[0][ni], 0, 0, 0); \
      acc[1][ni] = __builtin_amdgcn_mfma_f32_16x16x32_bf16(ah1, bh, acc[1][ni], 0, 0, 0); \
      acc[1][ni] = __builtin_amdgcn_mfma_f32_16x16x32_bf16(ah1, bl, acc[1][ni], 0, 0, 0); \
      acc[1][ni] = __builtin_amdgcn_mfma_f32_16x16x32_bf16(al1, bh, acc[1][ni], 0, 0, 0); \
    } } while (0)

  LDREG(A, 0);
  LDREG(B, 1);

  #pragma unroll 1
  for (int it = 0; it < 8; it += 2) {
    __syncthreads();
    STAGE(A);
    __syncthreads();
    if (it + 2 < 8) LDREG(A, it + 2);
    MFMAS();
    __syncthreads();
    STAGE(B);
    __syncthreads();
    if (it + 3 < 8) LDREG(B, it + 3);
    MFMAS();
  }
  #undef LDREG
  #undef STAGE
  #undef MFMAS

  // xnorm2 partial: 4 staging threads per row are lanes {l, l^1, l^2, l^3}
  float s = nacc;
  s += __shfl_xor(s, 1, 64);
  s += __shfl_xor(s, 2, 64);
  if ((tid & 3) == 0) xnp[ks * NTOK + t0 + sr] = s;

  // epilogue: transpose frags through LDS (reuse smem), coalesced plain stores.
  __syncthreads();
  float* lt = (float*)smem;   // 64 x LTS2 = 17408 B <= 20480
  const int tloc = tw + (lane >> 4) * 4;
  #pragma unroll
  for (int mi = 0; mi < 2; ++mi)
    #pragma unroll
    for (int ni = 0; ni < 2; ++ni)
      *(f32x4*)&lt[(ew + ni * 16 + fr) * LTS2 + tloc + mi * 16] = acc[mi][ni];
  __syncthreads();
  #pragma unroll
  for (int n = 0; n < 16; ++n) {
    const int f = tid + n * 256;
    const int e = f >> 6;
    const int t = f & 63;
    lp[(size_t)(ks * NEXP + e) * NTOK + t0 + t] = lt[e * LTS2 + t];
  }
}

// Sum 8 partials -> softmax/top-2 -> out/route/scatter/flags.
// v3: 512 threads / 64 tokens per block. Load phase: wave w = (ksplit-half, expert
// group), lane = token, coalesced; two-phase LDS combine (stride 65 -> conflict-free
// column reads). Epilogue: wave w handles tokens w*8..w*8+7, lane = expert,
// butterfly shuffle top-1/2/3 + Z (tie -> lowest index, matches serial scan).
__global__ __launch_bounds__(512)
void softmax2_kernel(const float* __restrict__ lp, const float* __restrict__ xnp,
                     const float* __restrict__ inv_nc, float* __restrict__ out,
                     int* __restrict__ route, int* __restrict__ nflag,
                     int* __restrict__ flags, int* __restrict__ cursor,
                     int* __restrict__ cnt, int* __restrict__ bucket,
                     int* __restrict__ posa) {
  __shared__ float lg[NEXP][65];   // 16.6 KB, stride 65: column read = 2-way free
  __shared__ float xn_s[64];
  __shared__ float snc[NEXP];
  const int tid  = threadIdx.x;
  const int lane = tid & 63;
  const int w    = tid >> 6;        // 0..7
  const int kg   = w >> 2;          // ksplit half: ksplits kg*4 .. kg*4+3
  const int eg   = (w & 3) * 16;    // expert group base
  const int t0   = blockIdx.x * 64;
  if (tid < NEXP) snc[tid] = inv_nc[tid];

  float p[16];
  {
    const int t = t0 + lane;
    const float* base = lp + (size_t)(kg * 4 * NEXP + eg) * NTOK + t;
    #pragma unroll
    for (int e = 0; e < 16; ++e) {
      const float* q = base + (size_t)e * NTOK;
      float a0 = q[0];
      float a1 = q[(size_t)NEXP * NTOK];
      float a2 = q[(size_t)2 * NEXP * NTOK];
      float a3 = q[(size_t)3 * NEXP * NTOK];
      p[e] = (a0 + a1) + (a2 + a3);
    }
    if (kg == 0) {
      #pragma unroll
      for (int e = 0; e < 16; ++e) lg[eg + e][lane] = p[e];
    }
  }
  __syncthreads();
  if (kg == 1) {
    #pragma unroll
    for (int e = 0; e < 16; ++e) lg[eg + e][lane] += p[e];
  }
  if (tid < 64) {
    float xs2 = 0.f;
    #pragma unroll
    for (int k = 0; k < 8; ++k) xs2 += xnp[k * NTOK + t0 + tid];
    xn_s[tid] = xs2;
  }
  __syncthreads();

  // wave-parallel epilogue: lane = expert
  #pragma unroll 1
  for (int j = 0; j < 8; ++j) {
    const int tl = w * 8 + j;
    const int t  = t0 + tl;
    const float inv_nx = 1.0f / fmaxf(sqrtf(xn_s[tl]), 1e-12f);
    const float l = lg[lane][tl] * snc[lane] * inv_nx;
    // top-1 (value, index), tie -> lowest index
    float v = l; int idx = lane;
    #pragma unroll
    for (int o = 32; o > 0; o >>= 1) {
      float ov = __shfl_xor(v, o, 64);
      int   oi = __shfl_xor(idx, o, 64);
      if (ov > v || (ov == v && oi < idx)) { v = ov; idx = oi; }
    }
    const float m1 = v; const int i1 = idx;
    v = (lane == i1) ? -1e30f : l; idx = lane;
    #pragma unroll
    for (int o = 32; o > 0; o >>= 1) {
      float ov = __shfl_xor(v, o, 64);
      int   oi = __shfl_xor(idx, o, 64);
      if (ov > v || (ov == v && oi < idx)) { v = ov; idx = oi; }
    }
    const float m2 = v; const int i2 = idx;
    v = (lane == i1 || lane == i2) ? -1e30f : l;
    #pragma unroll
    for (int o = 32; o > 0; o >>= 1) v = fmaxf(v, __shfl_xor(v, o, 64));
    const float m3 = v;
    float ze = expf(l - m1);
    #pragma unroll
    for (int o = 32; o > 0; o >>= 1) ze += __shfl_xor(ze, o, 64);
    if (lane == 0) {
      const float Z   = ze;
      const float p1w = 1.0f / Z;
      const float p2w = expf(m2 - m1) / Z;
      const float s2  = p1w + p2w + 1e-9f;
      out[t * 2 + 0] = (float)i1;
      out[t * 2 + 1] = (float)i2;
      out[2 * NTOK + t * 2 + 0] = p1w / s2;
      out[2 * NTOK + t * 2 + 1] = p2w / s2;
      route[t] = i1;
      const int p0 = atomicAdd(&cursor[i1], 1);
      atomicAdd(&cnt[i1], 1);
      if (p0 < MAXB) bucket[i1 * MAXB + p0] = t;
      posa[t] = p0;
      if ((m1 - m2) < TAU || (m2 - m3) < TAU) {
        int fidx = atomicAdd(nflag, 1);
        flags[fidx] = t;
      }
    }
  }
}

// Refine: block per flagged token; fp64 recompute + bucket fixup for flips.
__global__ __launch_bounds__(256)
void refine_np_kernel(const float* __restrict__ x, const float* __restrict__ bn,
                      float* __restrict__ out, int* __restrict__ route,
                      const int* __restrict__ nflag, const int* __restrict__ flags,
                      int* __restrict__ cursor, int* __restrict__ cnt,
                      int* __restrict__ bucket, int* __restrict__ posa) {
  __shared__ float a_lds[HDIM];
  __shared__ double redd[256];
  __shared__ float lf[NEXP];
  __shared__ float s_nx;
  const int tid  = threadIdx.x;
  const int lane = tid & 63;
  const int w    = tid >> 6;
  const int n = *nflag;
  for (int j = blockIdx.x; j < n; j += gridDim.x) {
    const int t = flags[j];
    const float* xr = x + (size_t)t * HDIM;
    double xacc = 0.0;
    #pragma unroll
    for (int i = 0; i < 8; ++i) {
      double v = (double)xr[tid + 256 * i];
      xacc += v * v;
    }
    double xn = block_reduce_sum_f64(xacc, redd);
    if (tid == 0) s_nx = (float)fmax(sqrt(xn), 1e-12);
    __syncthreads();
    const double nx = (double)s_nx;
    #pragma unroll
    for (int i = 0; i < 8; ++i) {
      int k = tid + 256 * i;
      a_lds[k] = (float)((double)xr[k] / nx);
    }
    __syncthreads();
    #pragma unroll 1
    for (int ei = 0; ei < 16; ++ei) {
      const int e = w * 16 + ei;
      const float* br = bn + (size_t)e * HDIM;
      double d = 0.0;
      #pragma unroll 8
      for (int i = 0; i < 32; ++i) {
        int k = lane + 64 * i;
        d += (double)a_lds[k] * (double)br[k];
      }
      #pragma unroll
      for (int o = 32; o > 0; o >>= 1) d += __shfl_down(d, o, 64);
      if (lane == 0) lf[e] = (float)d;
    }
    __syncthreads();
    if (tid == 0) {
      float m32 = lf[0];
      for (int ee = 1; ee < NEXP; ++ee) m32 = fmaxf(m32, lf[ee]);
      float ex[NEXP];
      for (int ee = 0; ee < NEXP; ++ee)
        ex[ee] = (float)exp((double)(lf[ee] - m32));
      float r[8];
      #pragma unroll
      for (int q = 0; q < 8; ++q) r[q] = ex[q];
      for (int i = 8; i < NEXP; i += 8)
        #pragma unroll
        for (int q = 0; q < 8; ++q) r[q] += ex[i + q];
      const float Z = ((r[0] + r[1]) + (r[2] + r[3])) + ((r[4] + r[5]) + (r[6] + r[7]));
      float p1 = -1.f, p2 = -1.f;
      int i1 = 0, i2 = 0;
      for (int ee = 0; ee < NEXP; ++ee) {
        float p = ex[ee] / Z;
        if (p > p1)      { p2 = p1; i2 = i1; p1 = p; i1 = ee; }
        else if (p > p2) { p2 = p; i2 = ee; }
      }
      const float s = (p1 + p2) + 1e-9f;
      out[t * 2 + 0] = (float)i1;
      out[t * 2 + 1] = (float)i2;
      out[2 * NTOK + t * 2 + 0] = p1 / s;
      out[2 * NTOK + t * 2 + 1] = p2 / s;
      const int old = route[t];
      if (i1 != old) {
        const int p_old = posa[t];
        if (p_old < MAXB) bucket[old * MAXB + p_old] = -1;   // punch hole
        atomicSub(&cnt[old], 1);
        const int p = atomicAdd(&cursor[i1], 1);
        atomicAdd(&cnt[i1], 1);
        if (p < MAXB) bucket[i1 * MAXB + p] = t;
        posa[t] = p;
        route[t] = i1;
      }
    }
    __syncthreads();
  }
}

// slow fallback refine (no bn dependency) for small-ws path
__global__ __launch_bounds__(64)
void refine_np_slow(const float* __restrict__ x, const float* __restrict__ c,
                    float* __restrict__ out, int* __restrict__ route,
                    const int* __restrict__ nflag, const int* __restrict__ flags) {
  __shared__ float lf[NEXP];
  const int e = threadIdx.x;
  const int n = *nflag;
  for (int j = blockIdx.x; j < n; j += gridDim.x) {
    const int t = flags[j];
    const float* xr = x + (size_t)t * HDIM;
    const float* cr = c + (size_t)e * HDIM;
    double xn = 0.0, cn = 0.0;
    for (int k = 0; k < HDIM; ++k) {
      double xv = (double)xr[k];
      double cv = (double)cr[k];
      xn += xv * xv;
      cn += cv * cv;
    }
    const float nx32 = (float)fmax(sqrt(xn), 1e-12);
    const float nc32 = (float)fmax(sqrt(cn), 1e-12);
    double d = 0.0;
    for (int k = 0; k < HDIM; ++k) {
      float a = (float)((double)xr[k] / (double)nx32);
      float b = (float)((double)cr[k] / (double)nc32);
      d += (double)a * (double)b;
    }
    lf[e] = (float)d;
    __syncthreads();
    if (e == 0) {
      float m32 = lf[0];
      for (int ee = 1; ee < NEXP; ++ee) m32 = fmaxf(m32, lf[ee]);
      float ex[NEXP];
      for (int ee = 0; ee < NEXP; ++ee)
        ex[ee] = (float)exp((double)(lf[ee] - m32));
      float r[8];
      #pragma unroll
      for (int q = 0; q < 8; ++q) r[q] = ex[q];
      for (int i = 8; i < NEXP; i += 8)
        #pragma unroll
        for (int q = 0; q < 8; ++q) r[q] += ex[i + q];
      const float Z = ((r[0] + r[1]) + (r[2] + r[3])) + ((r[4] + r[5]) + (r[6] + r[7]));
      float p1 = -1.f, p2 = -1.f;
      int i1 = 0, i2 = 0;
      for (int ee = 0; ee < NEXP; ++ee) {
        float p = ex[ee] / Z;
        if (p > p1)      { p2 = p1; i2 = i1; p1 = p; i1 = ee; }
        else if (p > p2) { p2 = p; i2 = ee; }
      }
      const float s = (p1 + p2) + 1e-9f;
      out[t * 2 + 0] = (float)i1;
      out[t * 2 + 1] = (float)i2;
      out[2 * NTOK + t * 2 + 0] = p1 / s;
      out[2 * NTOK + t * 2 + 1] = p2 / s;
      route[t] = i1;
    }
    __syncthreads();
  }
}

// Per-expert partial sums, 4-way token split. Skips -1 sentinel holes.
__global__ __launch_bounds__(256)
void segsum_part(const float* __restrict__ x, const int* __restrict__ cursor,
                 const int* __restrict__ bucket, float* __restrict__ psum) {
  __shared__ f32x4 part[4][64];
  const int e   = blockIdx.x >> 5;
  const int hc  = (blockIdx.x >> 2) & 7;
  const int ts  = blockIdx.x & 3;
  const int hb  = hc * 256;
  const int tid = threadIdx.x;
  const int rg  = tid >> 6;
  const int cc  = tid & 63;
  int n = cursor[e];
  if (n > MAXB) n = MAXB;
  const int nq = (n + 3) >> 2;
  const int lo = ts * nq;
  const int hi = min(lo + nq, n);
  const int* bk = bucket + e * MAXB;
  f32x4 a = (f32x4){0.f, 0.f, 0.f, 0.f};
  #pragma unroll 4
  for (int i = lo + rg; i < hi; i += 4) {
    const int r = bk[i];
    if (r >= 0) a += *(const f32x4*)(x + (size_t)r * HDIM + hb + cc * 4);
  }
  part[rg][cc] = a;
  __syncthreads();
  if (tid < 64) {
    f32x4 s = part[0][tid] + part[1][tid] + part[2][tid] + part[3][tid];
    *(f32x4*)&psum[(size_t)(ts * NEXP + e) * HDIM + hb + tid * 4] = s;
  }
}

__global__ __launch_bounds__(256)
void finalize4_kernel(const float* __restrict__ c, const float* __restrict__ psum,
                      const int* __restrict__ counts, float* __restrict__ out) {
  __shared__ float red[4];
  const int e = blockIdx.x;
  const int tid = threadIdx.x;
  const float cnt = (float)counts[e];
  const float minv = 1.0f / (cnt + 1e-6f);
  float u[8], cv[8];
  float ss = 0.f;
  #pragma unroll
  for (int j = 0; j < 8; ++j) {
    int h = tid + j * 256;
    cv[j] = c[e * HDIM + h];
    float sm = psum[(size_t)(0 * NEXP + e) * HDIM + h]
             + psum[(size_t)(1 * NEXP + e) * HDIM + h]
             + psum[(size_t)(2 * NEXP + e) * HDIM + h]
             + psum[(size_t)(3 * NEXP + e) * HDIM + h];
    float mean = sm * minv;
    u[j] = 0.9f * cv[j] + 0.1f * mean;
    ss += u[j] * u[j];
  }
  float tot = block_reduce_sum(ss, red);
  float sc = 1.0f / fmaxf(sqrtf(tot), 1e-12f);
  const bool nz = cnt > 0.f;
  #pragma unroll
  for (int j = 0; j < 8; ++j) {
    int h = tid + j * 256;
    out[4 * NTOK + e * HDIM + h] = nz ? u[j] * sc : cv[j];
  }
}

__global__ __launch_bounds__(256)
void finalize_kernel(const float* __restrict__ c, const float* __restrict__ sums,
                     const int* __restrict__ counts, float* __restrict__ out) {
  __shared__ float red[4];
  const int e = blockIdx.x;
  const int tid = threadIdx.x;
  const float cnt = (float)counts[e];
  const float minv = 1.0f / (cnt + 1e-6f);
  float u[8], cv[8];
  float ss = 0.f;
  #pragma unroll
  for (int j = 0; j < 8; ++j) {
    int h = tid + j * 256;
    cv[j] = c[e * HDIM + h];
    float mean = sums[e * HDIM + h] * minv;
    u[j] = 0.9f * cv[j] + 0.1f * mean;
    ss += u[j] * u[j];
  }
  float tot = block_reduce_sum(ss, red);
  float sc = 1.0f / fmaxf(sqrtf(tot), 1e-12f);
  const bool nz = cnt > 0.f;
  #pragma unroll
  for (int j = 0; j < 8; ++j) {
    int h = tid + j * 256;
    out[4 * NTOK + e * HDIM + h] = nz ? u[j] * sc : cv[j];
  }
}

// ---- fallback path kernels (small ws): R5 router + old segsum ----
__global__ __launch_bounds__(256)
void router_kernel(const float* __restrict__ x, const float* __restrict__ c,
                   const float* __restrict__ inv_nc, float* __restrict__ out,
                   int* __restrict__ route, int* __restrict__ nflag,
                   int* __restrict__ flags) {
  __shared__ __align__(16) float xs[64][36];
  __shared__ float lgs[64][67];
  const int tid  = threadIdx.x;
  const int lane = tid & 63;
  const int w    = tid >> 6;
  const int t0   = blockIdx.x * 64;
  const int e0   = __builtin_amdgcn_readfirstlane(w * 16);
  const float* cb = c + (size_t)e0 * HDIM;
  const int st = tid >> 3;
  const int sk = (tid & 7) * 4;
  float acc[16];
  #pragma unroll
  for (int e = 0; e < 16; ++e) acc[e] = 0.f;
  float nacc = 0.f;
  float4 p0 = *(const float4*)&x[(size_t)(t0 + st)      * HDIM + sk];
  float4 p1 = *(const float4*)&x[(size_t)(t0 + st + 32) * HDIM + sk];
  for (int k0 = 0; k0 < HDIM; k0 += 32) {
    __syncthreads();
    *(float4*)&xs[st][sk]      = p0;
    *(float4*)&xs[st + 32][sk] = p1;
    __syncthreads();
    const int kn = k0 + 32;
    if (kn < HDIM) {
      p0 = *(const float4*)&x[(size_t)(t0 + st)      * HDIM + kn + sk];
      p1 = *(const float4*)&x[(size_t)(t0 + st + 32) * HDIM + kn + sk];
    }
    float a[32];
    #pragma unroll
    for (int j = 0; j < 32; j += 4) {
      float4 v = *(const float4*)&xs[lane][j];
      a[j] = v.x; a[j+1] = v.y; a[j+2] = v.z; a[j+3] = v.w;
    }
    if (w == 0) {
      #pragma unroll
      for (int j = 0; j < 32; ++j) nacc += a[j] * a[j];
    }
    #pragma unroll
    for (int e = 0; e < 16; ++e) {
      const float* br = cb + (size_t)e * HDIM + k0;
      #pragma unroll
      for (int j = 0; j < 32; j += 4) {
        float4 bv = *(const float4*)&br[j];
        acc[e] += a[j]*bv.x + a[j+1]*bv.y + a[j+2]*bv.z + a[j+3]*bv.w;
      }
    }
  }
  #pragma unroll
  for (int e = 0; e < 16; ++e) lgs[lane][e0 + e] = acc[e] * inv_nc[e0 + e];
  __syncthreads();
  if (w == 0) {
    const float inv_nx = 1.0f / fmaxf(sqrtf(nacc), 1e-12f);
    float m1 = -1e30f, m2 = -1e30f, m3 = -1e30f;
    int i1 = 0, i2 = 0;
    for (int e = 0; e < NEXP; ++e) {
      float l = lgs[lane][e] * inv_nx;
      if (l > m1)      { m3 = m2; m2 = m1; i2 = i1; m1 = l; i1 = e; }
      else if (l > m2) { m3 = m2; m2 = l; i2 = e; }
      else if (l > m3) { m3 = l; }
    }
    float Z = 0.f;
    for (int e = 0; e < NEXP; ++e) Z += expf(lgs[lane][e] * inv_nx - m1);
    const float p1w = 1.0f / Z;
    const float p2w = expf(m2 - m1) / Z;
    const float s   = p1w + p2w + 1e-9f;
    const int tg = t0 + lane;
    out[tg * 2 + 0] = (float)i1;
    out[tg * 2 + 1] = (float)i2;
    out[2 * NTOK + tg * 2 + 0] = p1w / s;
    out[2 * NTOK + tg * 2 + 1] = p2w / s;
    route[tg] = i1;
    if ((m1 - m2) < TAU || (m2 - m3) < TAU) {
      int idx = atomicAdd(nflag, 1);
      flags[idx] = tg;
    }
  }
}

__global__ __launch_bounds__(512)
void segsum_kernel(const float* __restrict__ x, const int* __restrict__ route,
                   float* __restrict__ sums, int* __restrict__ counts) {
  __shared__ float ls[NEXP * 256];
  __shared__ int lcnt[NEXP];
  const int tid  = threadIdx.x;
  const int lane = tid & 63;
  const int w    = tid >> 6;
  const int hc   = blockIdx.x & 7;
  const int tg   = blockIdx.x >> 3;
  const int hb   = hc * 256;
  #pragma unroll
  for (int i = 0; i < 32; ++i) ls[tid + i * 512] = 0.f;
  if (tid < NEXP) lcnt[tid] = 0;
  __syncthreads();
  const int tbase = tg * 512 + w * 64;
  #pragma unroll 4
  for (int i = 0; i < 64; ++i) {
    const int t = tbase + i;
    const int e = route[t];
    const float* xr = x + (size_t)t * HDIM + hb + lane;
    #pragma unroll
    for (int j = 0; j < 4; ++j)
      atomicAdd(&ls[e * 256 + lane + 64 * j], xr[64 * j]);
    if (hc == 0 && lane == 0) atomicAdd(&lcnt[e], 1);
  }
  __syncthreads();
  #pragma unroll
  for (int i = tid; i < NEXP * 256; i += 512) {
    const int e = i >> 8, h = i & 255;
    atomicAdd(&sums[e * HDIM + hb + h], ls[i]);
  }
  if (hc == 0 && tid < NEXP && lcnt[tid] > 0) atomicAdd(&counts[tid], lcnt[tid]);
}

extern "C" void kernel_launch(void* const* d_in, const int* in_sizes, int n_in,
                              void* d_out, int out_size, void* d_ws, size_t ws_size,
                              hipStream_t stream) {
  const float* x = (const float*)d_in[0];
  const float* c = (const float*)d_in[1];
  float* out = (float*)d_out;
  float* ws = (float*)d_ws;

  float* inv_nc = ws;
  int*   cursor = (int*)(ws + 64);
  int*   nflag  = (int*)(ws + 128);
  int*   route  = (int*)(ws + 192);
  int*   flags  = (int*)(ws + 16576);
  float* sums   = ws + 32960;           // fallback path only
  float* bn     = ws + 164032;
  unsigned short* cbh = (unsigned short*)(ws + 295104);
  unsigned short* cbl = (unsigned short*)(ws + 360640);
  int*   bucket = (int*)(ws + 426176);
  float* psum   = ws + 557248;
  int*   posa   = (int*)(ws + 1081536);
  int*   cnt    = (int*)(ws + 1097920);
  float* lp     = ws + 1097984;
  float* xnp    = ws + 9486592;

  const size_t NEED = 9617664ull * 4ull;
  if (ws_size >= NEED) {
    cprep_kernel<<<NEXP, 256, 0, stream>>>(c, inv_nc, bn, cbh, cbl, cursor, cnt);
    gemm_part<<<2048, 256, 0, stream>>>(x, cbh, cbl, lp, xnp);
    softmax2_kernel<<<NTOK / 64, 512, 0, stream>>>(lp, xnp, inv_nc, out, route,
                                                   nflag, flags, cursor, cnt, bucket, posa);
    refine_np_kernel<<<512, 256, 0, stream>>>(x, bn, out, route, nflag, flags,
                                              cursor, cnt, bucket, posa);
    segsum_part<<<2048, 256, 0, stream>>>(x, cursor, bucket, psum);
    finalize4_kernel<<<NEXP, 256, 0, stream>>>(c, psum, cnt, out);
  } else {
    zero_kernel<<<1, 256, 0, stream>>>(ws + 64, 128);
    zero_kernel<<<512, 256, 0, stream>>>(sums, 131072);
    cnorm_kernel<<<NEXP, 256, 0, stream>>>(c, inv_nc);
    router_kernel<<<NTOK / 64, 256, 0, stream>>>(x, c, inv_nc, out, route, nflag, flags);
    refine_np_slow<<<1024, 64, 0, stream>>>(x, c, out, route, nflag, flags);
    segsum_kernel<<<256, 512, 0, stream>>>(x, route, sums, cursor);
    finalize_kernel<<<NEXP, 256, 0, stream>>>(c, sums, cursor, out);
  }
}

// Round 12
// 310.453 us; speedup vs baseline: 1.1383x; 1.1383x over previous
//
#include <hip/hip_runtime.h>
#include <math.h>

#define NTOK 16384
#define HDIM 2048
#define NEXP 64
#define KK   32
#define TAU  5e-5f
#define MAXB 2048    // bucket capacity per expert (mean 256, 112 sigma margin)
#define KP2  40      // LDS u16 row stride
#define LTS2 68      // epilogue f32 row stride

typedef __attribute__((ext_vector_type(8))) short short8;
typedef __attribute__((ext_vector_type(4))) float f32x4;
typedef __attribute__((ext_vector_type(2))) unsigned int uint2v;

// ws layout (4-byte units):
// [0..64)              inv_nc (f32)
// [64..128)            cursor (i32)
// [128..192)           nflag + pad (i32)
// [192..16576)         route  (i32)
// [16576..32960)       flags  (i32)
// [32960..164032)      sums   (f32, 64x2048)  (fallback path only)
// [164032..295104)     bn     (f32, 64x2048)
// [295104..360640)     cbh    (u16, 64x2048)
// [360640..426176)     cbl    (u16, 64x2048)
// [426176..557248)     bucket (i32, 64x2048)
// [557248..1081536)    psum   (f32, 4x64x2048)
// [1081536..1097920)   posa   (i32, 16384)
// [1097920..1097984)   cnt    (i32, 64)
// [1097984..9486592)   lp     (f32, 8x64x16384)  partial logits
// [9486592..9617664)   xnp    (f32, 8x16384)     partial xnorm2

__global__ __launch_bounds__(256)
void zero_kernel(float* p, int n) {
  int i = blockIdx.x * 256 + threadIdx.x;
  if (i < n) p[i] = 0.0f;
}

__device__ __forceinline__ float block_reduce_sum(float v, float* red) {
  #pragma unroll
  for (int o = 32; o > 0; o >>= 1) v += __shfl_down(v, o, 64);
  int lane = threadIdx.x & 63;
  int wid  = threadIdx.x >> 6;
  if (lane == 0) red[wid] = v;
  __syncthreads();
  float s = red[0] + red[1] + red[2] + red[3];
  __syncthreads();
  return s;
}

__device__ __forceinline__ double block_reduce_sum_f64(double v, double* red) {
  const int tid = threadIdx.x;
  red[tid] = v;
  __syncthreads();
  if (tid < 128) red[tid] += red[tid + 128];
  __syncthreads();
  if (tid < 64)  red[tid] += red[tid + 64];
  __syncthreads();
  double s = 0.0;
  if (tid < 64) {
    s = red[tid];
    #pragma unroll
    for (int o = 32; o > 0; o >>= 1) s += __shfl_down(s, o, 64);
  }
  if (tid == 0) red[0] = s;
  __syncthreads();
  s = red[0];
  __syncthreads();
  return s;
}

__global__ __launch_bounds__(256)
void cnorm_kernel(const float* __restrict__ c, float* __restrict__ inv_nc) {
  __shared__ float red[4];
  int e = blockIdx.x;
  float ss = 0.f;
  #pragma unroll
  for (int j = 0; j < 8; ++j) {
    float v = c[e * HDIM + threadIdx.x + j * 256];
    ss += v * v;
  }
  float tot = block_reduce_sum(ss, red);
  if (threadIdx.x == 0) inv_nc[e] = 1.0f / fmaxf(sqrtf(tot), 1e-12f);
}

// Center prep: fp32 inv-norm, fp64 bn, bf16 hi/lo split of c, zero counters.
__global__ __launch_bounds__(256)
void cprep_kernel(const float* __restrict__ c, float* __restrict__ inv_nc,
                  float* __restrict__ bn, unsigned short* __restrict__ cbh,
                  unsigned short* __restrict__ cbl, int* __restrict__ zr,
                  int* __restrict__ cnt) {
  __shared__ float red[4];
  __shared__ double redd[256];
  __shared__ float s_nc;
  const int e = blockIdx.x;
  const int tid = threadIdx.x;
  if (e == 0 && tid < 128) zr[tid] = 0;   // cursor[64] + nflag block
  if (e == 1 && tid < 64)  cnt[tid] = 0;
  const float* cr = c + (size_t)e * HDIM;
  float ss = 0.f;
  double acc = 0.0;
  #pragma unroll
  for (int j = 0; j < 8; ++j) {
    float v = cr[tid + j * 256];
    ss += v * v;
    double dv = (double)v;
    acc += dv * dv;
  }
  float tot = block_reduce_sum(ss, red);
  double cn = block_reduce_sum_f64(acc, redd);
  if (tid == 0) {
    inv_nc[e] = 1.0f / fmaxf(sqrtf(tot), 1e-12f);
    s_nc = (float)fmax(sqrt(cn), 1e-12);
  }
  __syncthreads();
  const double nc = (double)s_nc;
  #pragma unroll
  for (int j = 0; j < 8; ++j) {
    const int k = tid + j * 256;
    const float v = cr[k];
    bn[(size_t)e * HDIM + k] = (float)((double)v / nc);
    unsigned u = __float_as_uint(v);
    unsigned h = u & 0xffff0000u;
    float r = v - __uint_as_float(h);
    cbh[(size_t)e * HDIM + k] = (unsigned short)(u >> 16);
    cbl[(size_t)e * HDIM + k] = (unsigned short)(__float_as_uint(r) >> 16);
  }
}

// split fp32 pair into bf16 hi (truncation) + bf16 lo (truncated residual), packed 2-wide.
__device__ __forceinline__ void cvt2(float v0, float v1, unsigned &hi, unsigned &lo) {
  unsigned u0 = __float_as_uint(v0);
  unsigned u1 = __float_as_uint(v1);
  unsigned h0 = u0 & 0xffff0000u;
  unsigned h1 = u1 & 0xffff0000u;
  float r0 = v0 - __uint_as_float(h0);
  float r1 = v1 - __uint_as_float(h1);
  hi = (u0 >> 16) | h1;
  lo = (__float_as_uint(r0) >> 16) | (__float_as_uint(r1) & 0xffff0000u);
}

// K-split MFMA GEMM v2: block = 64 tokens x 64 experts x K=256. grid = 256 mt x 8 ks.
// 2-deep register prefetch (A/B sets): loads for it+2 issued right after staging,
// consumed two MFMA blocks later (~2 K-iters of latency slack). VGPR stays <128.
__global__ __launch_bounds__(256)
void gemm_part(const float* __restrict__ x,
               const unsigned short* __restrict__ cbh,
               const unsigned short* __restrict__ cbl,
               float* __restrict__ lp, float* __restrict__ xnp) {
  __shared__ __align__(16) unsigned short smem[10240];   // 20 KB
  unsigned short (*Ah)[KP2] = (unsigned short (*)[KP2])(smem);          // 64x40
  unsigned short (*Al)[KP2] = (unsigned short (*)[KP2])(smem + 2560);
  unsigned short (*Bh)[KP2] = (unsigned short (*)[KP2])(smem + 5120);
  unsigned short (*Bl)[KP2] = (unsigned short (*)[KP2])(smem + 7680);

  const int tid  = threadIdx.x;
  const int mt   = blockIdx.x >> 3;
  const int ks   = blockIdx.x & 7;
  const int t0   = mt * 64;
  const int kb   = ks * 256;
  const int sr   = tid >> 2;          // stage row 0..63 (A token / B expert)
  const int sq   = (tid & 3) * 8;     // stage col (8 elems)
  const int lane = tid & 63;
  const int w    = tid >> 6;
  const int tw   = (w & 1) * 32;
  const int ew   = (w >> 1) * 32;
  const int fr   = lane & 15;
  const int fk   = (lane >> 4) * 8;

  const float*          xrow  = x   + (size_t)(t0 + sr) * HDIM + kb + sq;
  const unsigned short* bhrow = cbh + (size_t)sr * HDIM + kb + sq;
  const unsigned short* blrow = cbl + (size_t)sr * HDIM + kb + sq;

  float nacc = 0.f;
  f32x4 Ax0, Ax1, Bx0, Bx1;
  short8 Abh, Abl, Bbh, Bbl;

  f32x4 acc[2][2];
  #pragma unroll
  for (int mi = 0; mi < 2; ++mi)
    #pragma unroll
    for (int ni = 0; ni < 2; ++ni)
      acc[mi][ni] = (f32x4){0.f, 0.f, 0.f, 0.f};

  #define LDREG(P, it_) do { const int o_ = (it_) * KK;                   \
    P##x0 = *(const f32x4*)(xrow + o_);                                   \
    P##x1 = *(const f32x4*)(xrow + o_ + 4);                               \
    P##bh = *(const short8*)(bhrow + o_);                                 \
    P##bl = *(const short8*)(blrow + o_); } while (0)

  #define STAGE(P) do {                                                   \
    unsigned h01, l01, h23, l23, h45, l45, h67, l67;                      \
    cvt2(P##x0.x, P##x0.y, h01, l01);                                     \
    cvt2(P##x0.z, P##x0.w, h23, l23);                                     \
    cvt2(P##x1.x, P##x1.y, h45, l45);                                     \
    cvt2(P##x1.z, P##x1.w, h67, l67);                                     \
    *(uint2v*)&Ah[sr][sq]     = (uint2v){h01, h23};                       \
    *(uint2v*)&Ah[sr][sq + 4] = (uint2v){h45, h67};                       \
    *(uint2v*)&Al[sr][sq]     = (uint2v){l01, l23};                       \
    *(uint2v*)&Al[sr][sq + 4] = (uint2v){l45, l67};                       \
    nacc += P##x0.x*P##x0.x + P##x0.y*P##x0.y + P##x0.z*P##x0.z + P##x0.w*P##x0.w \
          + P##x1.x*P##x1.x + P##x1.y*P##x1.y + P##x1.z*P##x1.z + P##x1.w*P##x1.w; \
    *(short8*)&Bh[sr][sq] = P##bh;                                        \
    *(short8*)&Bl[sr][sq] = P##bl; } while (0)

  #define MFMAS() do {                                                    \
    short8 ah0 = *(const short8*)&Ah[tw + fr][fk];                        \
    short8 ah1 = *(const short8*)&Ah[tw + 16 + fr][fk];                   \
    short8 al0 = *(const short8*)&Al[tw + fr][fk];                        \
    short8 al1 = *(const short8*)&Al[tw + 16 + fr][fk];                   \
    _Pragma("unroll")                                                     \
    for (int ni = 0; ni < 2; ++ni) {                                      \
      short8 bh = *(const short8*)&Bh[ew + ni * 16 + fr][fk];             \
      short8 bl = *(const short8*)&Bl[ew + ni * 16 + fr][fk];             \
      acc[0][ni] = __builtin_amdgcn_mfma_f32_16x16x32_bf16(ah0, bh, acc[0][ni], 0, 0, 0); \
      acc[0][ni] = __builtin_amdgcn_mfma_f32_16x16x32_bf16(ah0, bl, acc[0][ni], 0, 0, 0); \
      acc[0][ni] = __builtin_amdgcn_mfma_f32_16x16x32_bf16(al0, bh, acc[0][ni], 0, 0, 0); \
      acc[1][ni] = __builtin_amdgcn_mfma_f32_16x16x32_bf16(ah1, bh, acc[1][ni], 0, 0, 0); \
      acc[1][ni] = __builtin_amdgcn_mfma_f32_16x16x32_bf16(ah1, bl, acc[1][ni], 0, 0, 0); \
      acc[1][ni] = __builtin_amdgcn_mfma_f32_16x16x32_bf16(al1, bh, acc[1][ni], 0, 0, 0); \
    } } while (0)

  LDREG(A, 0);
  LDREG(B, 1);

  #pragma unroll 1
  for (int it = 0; it < 8; it += 2) {
    __syncthreads();
    STAGE(A);
    __syncthreads();
    if (it + 2 < 8) LDREG(A, it + 2);
    MFMAS();
    __syncthreads();
    STAGE(B);
    __syncthreads();
    if (it + 3 < 8) LDREG(B, it + 3);
    MFMAS();
  }
  #undef LDREG
  #undef STAGE
  #undef MFMAS

  // xnorm2 partial: 4 staging threads per row are lanes {l, l^1, l^2, l^3}
  float s = nacc;
  s += __shfl_xor(s, 1, 64);
  s += __shfl_xor(s, 2, 64);
  if ((tid & 3) == 0) xnp[ks * NTOK + t0 + sr] = s;

  // epilogue: transpose frags through LDS (reuse smem), coalesced plain stores.
  __syncthreads();
  float* lt = (float*)smem;   // 64 x LTS2 = 17408 B <= 20480
  const int tloc = tw + (lane >> 4) * 4;
  #pragma unroll
  for (int mi = 0; mi < 2; ++mi)
    #pragma unroll
    for (int ni = 0; ni < 2; ++ni)
      *(f32x4*)&lt[(ew + ni * 16 + fr) * LTS2 + tloc + mi * 16] = acc[mi][ni];
  __syncthreads();
  #pragma unroll
  for (int n = 0; n < 16; ++n) {
    const int f = tid + n * 256;
    const int e = f >> 6;
    const int t = f & 63;
    lp[(size_t)(ks * NEXP + e) * NTOK + t0 + t] = lt[e * LTS2 + t];
  }
}

// Sum 8 partials -> softmax/top-2 -> out/route/scatter/flags.
// v2 (round-9 verified): 512 threads / 64 tokens per block, grid 256 -> 2048 waves.
// Wave w: ksplit half kg=w>>2 (4 ksplits), expert group eg=(w&3)*16.
// Lane = token. 64 independent coalesced loads/thread, p[16] regs.
// Two-phase LDS combine (no atomics), epilogue on lanes 0..63.
__global__ __launch_bounds__(512)
void softmax2_kernel(const float* __restrict__ lp, const float* __restrict__ xnp,
                     const float* __restrict__ inv_nc, float* __restrict__ out,
                     int* __restrict__ route, int* __restrict__ nflag,
                     int* __restrict__ flags, int* __restrict__ cursor,
                     int* __restrict__ cnt, int* __restrict__ bucket,
                     int* __restrict__ posa) {
  __shared__ float lg[NEXP][68];   // 17.4 KB, stride 68 -> conflict-free
  __shared__ float snc[NEXP];
  const int tid  = threadIdx.x;
  const int lane = tid & 63;
  const int w    = tid >> 6;        // 0..7
  const int kg   = w >> 2;          // ksplit half: ksplits kg*4 .. kg*4+3
  const int eg   = (w & 3) * 16;    // expert group base
  const int t0   = blockIdx.x * 64;
  const int t    = t0 + lane;
  if (tid < NEXP) snc[tid] = inv_nc[tid];

  float p[16];
  const float* base = lp + (size_t)(kg * 4 * NEXP + eg) * NTOK + t;
  #pragma unroll
  for (int e = 0; e < 16; ++e) {
    const float* q = base + (size_t)e * NTOK;
    float a0 = q[0];
    float a1 = q[(size_t)NEXP * NTOK];
    float a2 = q[(size_t)2 * NEXP * NTOK];
    float a3 = q[(size_t)3 * NEXP * NTOK];
    p[e] = (a0 + a1) + (a2 + a3);
  }
  if (kg == 0) {
    #pragma unroll
    for (int e = 0; e < 16; ++e) lg[eg + e][lane] = p[e];
  }
  __syncthreads();
  if (kg == 1) {
    #pragma unroll
    for (int e = 0; e < 16; ++e) lg[eg + e][lane] += p[e];
  }
  __syncthreads();

  if (tid < 64) {
    float xs2 = 0.f;
    #pragma unroll
    for (int k = 0; k < 8; ++k) xs2 += xnp[k * NTOK + t];
    const float inv_nx = 1.0f / fmaxf(sqrtf(xs2), 1e-12f);
    float m1 = -1e30f, m2 = -1e30f, m3 = -1e30f;
    int i1 = 0, i2 = 0;
    #pragma unroll
    for (int e = 0; e < NEXP; ++e) {
      float l = lg[e][lane] * snc[e] * inv_nx;
      if (l > m1)      { m3 = m2; m2 = m1; i2 = i1; m1 = l; i1 = e; }
      else if (l > m2) { m3 = m2; m2 = l; i2 = e; }
      else if (l > m3) { m3 = l; }
    }
    float Z = 0.f;
    #pragma unroll
    for (int e = 0; e < NEXP; ++e)
      Z += expf(lg[e][lane] * snc[e] * inv_nx - m1);
    const float p1w = 1.0f / Z;
    const float p2w = expf(m2 - m1) / Z;
    const float s2  = p1w + p2w + 1e-9f;
    out[t * 2 + 0] = (float)i1;
    out[t * 2 + 1] = (float)i2;
    out[2 * NTOK + t * 2 + 0] = p1w / s2;
    out[2 * NTOK + t * 2 + 1] = p2w / s2;
    route[t] = i1;
    const int p0 = atomicAdd(&cursor[i1], 1);
    atomicAdd(&cnt[i1], 1);
    if (p0 < MAXB) bucket[i1 * MAXB + p0] = t;
    posa[t] = p0;
    if ((m1 - m2) < TAU || (m2 - m3) < TAU) {
      int idx = atomicAdd(nflag, 1);
      flags[idx] = t;
    }
  }
}

// Refine: block per flagged token; fp64 recompute + bucket fixup for flips.
__global__ __launch_bounds__(256)
void refine_np_kernel(const float* __restrict__ x, const float* __restrict__ bn,
                      float* __restrict__ out, int* __restrict__ route,
                      const int* __restrict__ nflag, const int* __restrict__ flags,
                      int* __restrict__ cursor, int* __restrict__ cnt,
                      int* __restrict__ bucket, int* __restrict__ posa) {
  __shared__ float a_lds[HDIM];
  __shared__ double redd[256];
  __shared__ float lf[NEXP];
  __shared__ float s_nx;
  const int tid  = threadIdx.x;
  const int lane = tid & 63;
  const int w    = tid >> 6;
  const int n = *nflag;
  for (int j = blockIdx.x; j < n; j += gridDim.x) {
    const int t = flags[j];
    const float* xr = x + (size_t)t * HDIM;
    double xacc = 0.0;
    #pragma unroll
    for (int i = 0; i < 8; ++i) {
      double v = (double)xr[tid + 256 * i];
      xacc += v * v;
    }
    double xn = block_reduce_sum_f64(xacc, redd);
    if (tid == 0) s_nx = (float)fmax(sqrt(xn), 1e-12);
    __syncthreads();
    const double nx = (double)s_nx;
    #pragma unroll
    for (int i = 0; i < 8; ++i) {
      int k = tid + 256 * i;
      a_lds[k] = (float)((double)xr[k] / nx);
    }
    __syncthreads();
    #pragma unroll 1
    for (int ei = 0; ei < 16; ++ei) {
      const int e = w * 16 + ei;
      const float* br = bn + (size_t)e * HDIM;
      double d = 0.0;
      #pragma unroll 8
      for (int i = 0; i < 32; ++i) {
        int k = lane + 64 * i;
        d += (double)a_lds[k] * (double)br[k];
      }
      #pragma unroll
      for (int o = 32; o > 0; o >>= 1) d += __shfl_down(d, o, 64);
      if (lane == 0) lf[e] = (float)d;
    }
    __syncthreads();
    if (tid == 0) {
      float m32 = lf[0];
      for (int ee = 1; ee < NEXP; ++ee) m32 = fmaxf(m32, lf[ee]);
      float ex[NEXP];
      for (int ee = 0; ee < NEXP; ++ee)
        ex[ee] = (float)exp((double)(lf[ee] - m32));
      float r[8];
      #pragma unroll
      for (int q = 0; q < 8; ++q) r[q] = ex[q];
      for (int i = 8; i < NEXP; i += 8)
        #pragma unroll
        for (int q = 0; q < 8; ++q) r[q] += ex[i + q];
      const float Z = ((r[0] + r[1]) + (r[2] + r[3])) + ((r[4] + r[5]) + (r[6] + r[7]));
      float p1 = -1.f, p2 = -1.f;
      int i1 = 0, i2 = 0;
      for (int ee = 0; ee < NEXP; ++ee) {
        float p = ex[ee] / Z;
        if (p > p1)      { p2 = p1; i2 = i1; p1 = p; i1 = ee; }
        else if (p > p2) { p2 = p; i2 = ee; }
      }
      const float s = (p1 + p2) + 1e-9f;
      out[t * 2 + 0] = (float)i1;
      out[t * 2 + 1] = (float)i2;
      out[2 * NTOK + t * 2 + 0] = p1 / s;
      out[2 * NTOK + t * 2 + 1] = p2 / s;
      const int old = route[t];
      if (i1 != old) {
        const int p_old = posa[t];
        if (p_old < MAXB) bucket[old * MAXB + p_old] = -1;   // punch hole
        atomicSub(&cnt[old], 1);
        const int p = atomicAdd(&cursor[i1], 1);
        atomicAdd(&cnt[i1], 1);
        if (p < MAXB) bucket[i1 * MAXB + p] = t;
        posa[t] = p;
        route[t] = i1;
      }
    }
    __syncthreads();
  }
}

// slow fallback refine (no bn dependency) for small-ws path
__global__ __launch_bounds__(64)
void refine_np_slow(const float* __restrict__ x, const float* __restrict__ c,
                    float* __restrict__ out, int* __restrict__ route,
                    const int* __restrict__ nflag, const int* __restrict__ flags) {
  __shared__ float lf[NEXP];
  const int e = threadIdx.x;
  const int n = *nflag;
  for (int j = blockIdx.x; j < n; j += gridDim.x) {
    const int t = flags[j];
    const float* xr = x + (size_t)t * HDIM;
    const float* cr = c + (size_t)e * HDIM;
    double xn = 0.0, cn = 0.0;
    for (int k = 0; k < HDIM; ++k) {
      double xv = (double)xr[k];
      double cv = (double)cr[k];
      xn += xv * xv;
      cn += cv * cv;
    }
    const float nx32 = (float)fmax(sqrt(xn), 1e-12);
    const float nc32 = (float)fmax(sqrt(cn), 1e-12);
    double d = 0.0;
    for (int k = 0; k < HDIM; ++k) {
      float a = (float)((double)xr[k] / (double)nx32);
      float b = (float)((double)cr[k] / (double)nc32);
      d += (double)a * (double)b;
    }
    lf[e] = (float)d;
    __syncthreads();
    if (e == 0) {
      float m32 = lf[0];
      for (int ee = 1; ee < NEXP; ++ee) m32 = fmaxf(m32, lf[ee]);
      float ex[NEXP];
      for (int ee = 0; ee < NEXP; ++ee)
        ex[ee] = (float)exp((double)(lf[ee] - m32));
      float r[8];
      #pragma unroll
      for (int q = 0; q < 8; ++q) r[q] = ex[q];
      for (int i = 8; i < NEXP; i += 8)
        #pragma unroll
        for (int q = 0; q < 8; ++q) r[q] += ex[i + q];
      const float Z = ((r[0] + r[1]) + (r[2] + r[3])) + ((r[4] + r[5]) + (r[6] + r[7]));
      float p1 = -1.f, p2 = -1.f;
      int i1 = 0, i2 = 0;
      for (int ee = 0; ee < NEXP; ++ee) {
        float p = ex[ee] / Z;
        if (p > p1)      { p2 = p1; i2 = i1; p1 = p; i1 = ee; }
        else if (p > p2) { p2 = p; i2 = ee; }
      }
      const float s = (p1 + p2) + 1e-9f;
      out[t * 2 + 0] = (float)i1;
      out[t * 2 + 1] = (float)i2;
      out[2 * NTOK + t * 2 + 0] = p1 / s;
      out[2 * NTOK + t * 2 + 1] = p2 / s;
      route[t] = i1;
    }
    __syncthreads();
  }
}

// Per-expert partial sums, 4-way token split. Skips -1 sentinel holes.
__global__ __launch_bounds__(256)
void segsum_part(const float* __restrict__ x, const int* __restrict__ cursor,
                 const int* __restrict__ bucket, float* __restrict__ psum) {
  __shared__ f32x4 part[4][64];
  const int e   = blockIdx.x >> 5;
  const int hc  = (blockIdx.x >> 2) & 7;
  const int ts  = blockIdx.x & 3;
  const int hb  = hc * 256;
  const int tid = threadIdx.x;
  const int rg  = tid >> 6;
  const int cc  = tid & 63;
  int n = cursor[e];
  if (n > MAXB) n = MAXB;
  const int nq = (n + 3) >> 2;
  const int lo = ts * nq;
  const int hi = min(lo + nq, n);
  const int* bk = bucket + e * MAXB;
  f32x4 a = (f32x4){0.f, 0.f, 0.f, 0.f};
  #pragma unroll 4
  for (int i = lo + rg; i < hi; i += 4) {
    const int r = bk[i];
    if (r >= 0) a += *(const f32x4*)(x + (size_t)r * HDIM + hb + cc * 4);
  }
  part[rg][cc] = a;
  __syncthreads();
  if (tid < 64) {
    f32x4 s = part[0][tid] + part[1][tid] + part[2][tid] + part[3][tid];
    *(f32x4*)&psum[(size_t)(ts * NEXP + e) * HDIM + hb + tid * 4] = s;
  }
}

__global__ __launch_bounds__(256)
void finalize4_kernel(const float* __restrict__ c, const float* __restrict__ psum,
                      const int* __restrict__ counts, float* __restrict__ out) {
  __shared__ float red[4];
  const int e = blockIdx.x;
  const int tid = threadIdx.x;
  const float cnt = (float)counts[e];
  const float minv = 1.0f / (cnt + 1e-6f);
  float u[8], cv[8];
  float ss = 0.f;
  #pragma unroll
  for (int j = 0; j < 8; ++j) {
    int h = tid + j * 256;
    cv[j] = c[e * HDIM + h];
    float sm = psum[(size_t)(0 * NEXP + e) * HDIM + h]
             + psum[(size_t)(1 * NEXP + e) * HDIM + h]
             + psum[(size_t)(2 * NEXP + e) * HDIM + h]
             + psum[(size_t)(3 * NEXP + e) * HDIM + h];
    float mean = sm * minv;
    u[j] = 0.9f * cv[j] + 0.1f * mean;
    ss += u[j] * u[j];
  }
  float tot = block_reduce_sum(ss, red);
  float sc = 1.0f / fmaxf(sqrtf(tot), 1e-12f);
  const bool nz = cnt > 0.f;
  #pragma unroll
  for (int j = 0; j < 8; ++j) {
    int h = tid + j * 256;
    out[4 * NTOK + e * HDIM + h] = nz ? u[j] * sc : cv[j];
  }
}

__global__ __launch_bounds__(256)
void finalize_kernel(const float* __restrict__ c, const float* __restrict__ sums,
                     const int* __restrict__ counts, float* __restrict__ out) {
  __shared__ float red[4];
  const int e = blockIdx.x;
  const int tid = threadIdx.x;
  const float cnt = (float)counts[e];
  const float minv = 1.0f / (cnt + 1e-6f);
  float u[8], cv[8];
  float ss = 0.f;
  #pragma unroll
  for (int j = 0; j < 8; ++j) {
    int h = tid + j * 256;
    cv[j] = c[e * HDIM + h];
    float mean = sums[e * HDIM + h] * minv;
    u[j] = 0.9f * cv[j] + 0.1f * mean;
    ss += u[j] * u[j];
  }
  float tot = block_reduce_sum(ss, red);
  float sc = 1.0f / fmaxf(sqrtf(tot), 1e-12f);
  const bool nz = cnt > 0.f;
  #pragma unroll
  for (int j = 0; j < 8; ++j) {
    int h = tid + j * 256;
    out[4 * NTOK + e * HDIM + h] = nz ? u[j] * sc : cv[j];
  }
}

// ---- fallback path kernels (small ws): R5 router + old segsum ----
__global__ __launch_bounds__(256)
void router_kernel(const float* __restrict__ x, const float* __restrict__ c,
                   const float* __restrict__ inv_nc, float* __restrict__ out,
                   int* __restrict__ route, int* __restrict__ nflag,
                   int* __restrict__ flags) {
  __shared__ __align__(16) float xs[64][36];
  __shared__ float lgs[64][67];
  const int tid  = threadIdx.x;
  const int lane = tid & 63;
  const int w    = tid >> 6;
  const int t0   = blockIdx.x * 64;
  const int e0   = __builtin_amdgcn_readfirstlane(w * 16);
  const float* cb = c + (size_t)e0 * HDIM;
  const int st = tid >> 3;
  const int sk = (tid & 7) * 4;
  float acc[16];
  #pragma unroll
  for (int e = 0; e < 16; ++e) acc[e] = 0.f;
  float nacc = 0.f;
  float4 p0 = *(const float4*)&x[(size_t)(t0 + st)      * HDIM + sk];
  float4 p1 = *(const float4*)&x[(size_t)(t0 + st + 32) * HDIM + sk];
  for (int k0 = 0; k0 < HDIM; k0 += 32) {
    __syncthreads();
    *(float4*)&xs[st][sk]      = p0;
    *(float4*)&xs[st + 32][sk] = p1;
    __syncthreads();
    const int kn = k0 + 32;
    if (kn < HDIM) {
      p0 = *(const float4*)&x[(size_t)(t0 + st)      * HDIM + kn + sk];
      p1 = *(const float4*)&x[(size_t)(t0 + st + 32) * HDIM + kn + sk];
    }
    float a[32];
    #pragma unroll
    for (int j = 0; j < 32; j += 4) {
      float4 v = *(const float4*)&xs[lane][j];
      a[j] = v.x; a[j+1] = v.y; a[j+2] = v.z; a[j+3] = v.w;
    }
    if (w == 0) {
      #pragma unroll
      for (int j = 0; j < 32; ++j) nacc += a[j] * a[j];
    }
    #pragma unroll
    for (int e = 0; e < 16; ++e) {
      const float* br = cb + (size_t)e * HDIM + k0;
      #pragma unroll
      for (int j = 0; j < 32; j += 4) {
        float4 bv = *(const float4*)&br[j];
        acc[e] += a[j]*bv.x + a[j+1]*bv.y + a[j+2]*bv.z + a[j+3]*bv.w;
      }
    }
  }
  #pragma unroll
  for (int e = 0; e < 16; ++e) lgs[lane][e0 + e] = acc[e] * inv_nc[e0 + e];
  __syncthreads();
  if (w == 0) {
    const float inv_nx = 1.0f / fmaxf(sqrtf(nacc), 1e-12f);
    float m1 = -1e30f, m2 = -1e30f, m3 = -1e30f;
    int i1 = 0, i2 = 0;
    for (int e = 0; e < NEXP; ++e) {
      float l = lgs[lane][e] * inv_nx;
      if (l > m1)      { m3 = m2; m2 = m1; i2 = i1; m1 = l; i1 = e; }
      else if (l > m2) { m3 = m2; m2 = l; i2 = e; }
      else if (l > m3) { m3 = l; }
    }
    float Z = 0.f;
    for (int e = 0; e < NEXP; ++e) Z += expf(lgs[lane][e] * inv_nx - m1);
    const float p1w = 1.0f / Z;
    const float p2w = expf(m2 - m1) / Z;
    const float s   = p1w + p2w + 1e-9f;
    const int tg = t0 + lane;
    out[tg * 2 + 0] = (float)i1;
    out[tg * 2 + 1] = (float)i2;
    out[2 * NTOK + tg * 2 + 0] = p1w / s;
    out[2 * NTOK + tg * 2 + 1] = p2w / s;
    route[tg] = i1;
    if ((m1 - m2) < TAU || (m2 - m3) < TAU) {
      int idx = atomicAdd(nflag, 1);
      flags[idx] = tg;
    }
  }
}

__global__ __launch_bounds__(512)
void segsum_kernel(const float* __restrict__ x, const int* __restrict__ route,
                   float* __restrict__ sums, int* __restrict__ counts) {
  __shared__ float ls[NEXP * 256];
  __shared__ int lcnt[NEXP];
  const int tid  = threadIdx.x;
  const int lane = tid & 63;
  const int w    = tid >> 6;
  const int hc   = blockIdx.x & 7;
  const int tg   = blockIdx.x >> 3;
  const int hb   = hc * 256;
  #pragma unroll
  for (int i = 0; i < 32; ++i) ls[tid + i * 512] = 0.f;
  if (tid < NEXP) lcnt[tid] = 0;
  __syncthreads();
  const int tbase = tg * 512 + w * 64;
  #pragma unroll 4
  for (int i = 0; i < 64; ++i) {
    const int t = tbase + i;
    const int e = route[t];
    const float* xr = x + (size_t)t * HDIM + hb + lane;
    #pragma unroll
    for (int j = 0; j < 4; ++j)
      atomicAdd(&ls[e * 256 + lane + 64 * j], xr[64 * j]);
    if (hc == 0 && lane == 0) atomicAdd(&lcnt[e], 1);
  }
  __syncthreads();
  #pragma unroll
  for (int i = tid; i < NEXP * 256; i += 512) {
    const int e = i >> 8, h = i & 255;
    atomicAdd(&sums[e * HDIM + hb + h], ls[i]);
  }
  if (hc == 0 && tid < NEXP && lcnt[tid] > 0) atomicAdd(&counts[tid], lcnt[tid]);
}

extern "C" void kernel_launch(void* const* d_in, const int* in_sizes, int n_in,
                              void* d_out, int out_size, void* d_ws, size_t ws_size,
                              hipStream_t stream) {
  const float* x = (const float*)d_in[0];
  const float* c = (const float*)d_in[1];
  float* out = (float*)d_out;
  float* ws = (float*)d_ws;

  float* inv_nc = ws;
  int*   cursor = (int*)(ws + 64);
  int*   nflag  = (int*)(ws + 128);
  int*   route  = (int*)(ws + 192);
  int*   flags  = (int*)(ws + 16576);
  float* sums   = ws + 32960;           // fallback path only
  float* bn     = ws + 164032;
  unsigned short* cbh = (unsigned short*)(ws + 295104);
  unsigned short* cbl = (unsigned short*)(ws + 360640);
  int*   bucket = (int*)(ws + 426176);
  float* psum   = ws + 557248;
  int*   posa   = (int*)(ws + 1081536);
  int*   cnt    = (int*)(ws + 1097920);
  float* lp     = ws + 1097984;
  float* xnp    = ws + 9486592;

  const size_t NEED = 9617664ull * 4ull;
  if (ws_size >= NEED) {
    cprep_kernel<<<NEXP, 256, 0, stream>>>(c, inv_nc, bn, cbh, cbl, cursor, cnt);
    gemm_part<<<2048, 256, 0, stream>>>(x, cbh, cbl, lp, xnp);
    softmax2_kernel<<<NTOK / 64, 512, 0, stream>>>(lp, xnp, inv_nc, out, route,
                                                   nflag, flags, cursor, cnt, bucket, posa);
    refine_np_kernel<<<512, 256, 0, stream>>>(x, bn, out, route, nflag, flags,
                                              cursor, cnt, bucket, posa);
    segsum_part<<<2048, 256, 0, stream>>>(x, cursor, bucket, psum);
    finalize4_kernel<<<NEXP, 256, 0, stream>>>(c, psum, cnt, out);
  } else {
    zero_kernel<<<1, 256, 0, stream>>>(ws + 64, 128);
    zero_kernel<<<512, 256, 0, stream>>>(sums, 131072);
    cnorm_kernel<<<NEXP, 256, 0, stream>>>(c, inv_nc);
    router_kernel<<<NTOK / 64, 256, 0, stream>>>(x, c, inv_nc, out, route, nflag, flags);
    refine_np_slow<<<1024, 64, 0, stream>>>(x, c, out, route, nflag, flags);
    segsum_kernel<<<256, 512, 0, stream>>>(x, route, sums, cursor);
    finalize_kernel<<<NEXP, 256, 0, stream>>>(c, sums, cursor, out);
  }
}